// Round 3
// baseline (433.979 us; speedup 1.0000x reference)
//
#include <hip/hip_runtime.h>

// network_5299989643808: per-(z,zp) tiny MLP over B observations.
// B=2048, Z=64, IDIM=2, HDIM=4, NOPT=4. f32 in / f32 out.
// Outputs concat flat: pi [B,Z,Z,4], log_pi [B,Z,Z,4], xi [B,Z,Z,4].
//
// R3: wave = one (z,zp) pair, lanes = 64 batch rows.
//  - LN affines folded into W2/b2 and Wpi/Wxi/bpi/bxi (LN output enters the
//    next layer linearly) -> 72 wave-uniform weights -> SGPRs via
//    readfirstlane, computed once per wave. Per-thread VGPRs ~35.
//  - __launch_bounds__(512,8): 8 waves/SIMD (R1/R2 were stuck at <=4 because
//    88 weight floats lived in per-lane VGPRs).
//  - block = 8 waves = 8 consecutive pairs; outputs transposed through LDS
//    (stage[b][pair][12], pad stride 100 floats = conflict-free b128 both
//    ways) so global stores are full-128B-line segments (write BW preserved).
//  - nt reads are stride-256B gathers but nt (512KB) is L2-hot; 2 loads per
//    ~190-instr MLP.

#define ZD 64
#define BD 2048
#define NPAIR (ZD * ZD)                     // 4096
#define OFFW ((size_t)BD * NPAIR * 4)       // floats per output tensor
#define NCHUNK 16                           // 1024 b per block / 64 lanes

#define LOG2E 1.4426950408889634f
#define LN2   0.6931471805599453f

__device__ __forceinline__ float rf(float x) {
    return __int_as_float(__builtin_amdgcn_readfirstlane(__float_as_int(x)));
}

__device__ __forceinline__ float fast_exp(float x) {
    return __builtin_amdgcn_exp2f(x * LOG2E);
}

__device__ __forceinline__ float fast_tanh(float x) {
    float y = fminf(fmaxf(x, -9.0f), 9.0f);
    float t = __builtin_amdgcn_exp2f(y * (2.0f * LOG2E));
    return (t - 1.0f) * __builtin_amdgcn_rcpf(t + 1.0f);
}

__global__ __launch_bounds__(512, 8) void net_kernel(
    const float* __restrict__ nt,
    const float* __restrict__ W1,  const float* __restrict__ b1,
    const float* __restrict__ g1,  const float* __restrict__ be1,
    const float* __restrict__ W2,  const float* __restrict__ b2,
    const float* __restrict__ g2,  const float* __restrict__ be2,
    const float* __restrict__ Wpi, const float* __restrict__ bpi,
    const float* __restrict__ Wxi, const float* __restrict__ bxi,
    float* __restrict__ out)
{
    const int tid   = threadIdx.x;
    const int lane  = tid & 63;
    const int w     = tid >> 6;               // wave id 0..7 = pair slot
    const int pg    = blockIdx.x >> 1;        // pair-group 0..511
    const int bh    = blockIdx.x & 1;         // b-half
    const int p0    = pg * 8;                 // 8 consecutive pairs, same z
    const int z     = p0 >> 6;                // wave/block-uniform
    const int zpb   = p0 & 63;                // zp base (multiple of 8)
    const int p     = p0 + w;                 // this wave's pair
    const int bbase = bh * (BD / 2);

    // stage[b][pair][stream][4] with padded b-stride of 100 floats:
    // write (lane=b, wave=pair): stride 400B -> 16B-offset walk mod 128B, ok
    // read  (tid= b*8+s):        chunk-col (25b+3s+st)%8 spreads, ok
    __shared__ float stage[64 * 100];

    // ---------- one-time: fold weights -> wave-uniform SGPR scalars --------
    float s_w1a[4], s_w1b[4], s_b1[4];
    #pragma unroll
    for (int i = 0; i < 4; ++i) {
        s_w1a[i] = rf(W1[p * 8 + i]);
        s_w1b[i] = rf(W1[p * 8 + 4 + i]);
        s_b1[i]  = rf(b1[p * 4 + i]);
    }
    __builtin_amdgcn_sched_barrier(0);

    float s_W2[16], s_b2[4];
    {
        float g[4], be[4];
        #pragma unroll
        for (int i = 0; i < 4; ++i) { g[i] = g1[p * 4 + i]; be[i] = be1[p * 4 + i]; }
        #pragma unroll
        for (int k = 0; k < 4; ++k) {
            float acc = b2[p * 4 + k];
            #pragma unroll
            for (int i = 0; i < 4; ++i) {
                float wv = W2[p * 16 + i * 4 + k];
                s_W2[i * 4 + k] = rf(g[i] * wv);
                acc = fmaf(be[i], wv, acc);
            }
            s_b2[k] = rf(acc);
        }
    }
    __builtin_amdgcn_sched_barrier(0);

    float s_Wp[16], s_bp[4], s_Wx[16], s_bx[4];
    {
        float g[4], be[4];
        #pragma unroll
        for (int i = 0; i < 4; ++i) { g[i] = g2[p * 4 + i]; be[i] = be2[p * 4 + i]; }
        #pragma unroll
        for (int o = 0; o < 4; ++o) {
            float ap = bpi[p * 4 + o];
            float ax = bxi[p * 4 + o];
            #pragma unroll
            for (int k = 0; k < 4; ++k) {
                float wp = Wpi[p * 16 + k * 4 + o];
                float wx = Wxi[p * 16 + k * 4 + o];
                s_Wp[k * 4 + o] = rf(g[k] * wp);
                s_Wx[k * 4 + o] = rf(g[k] * wx);
                ap = fmaf(be[k], wp, ap);
                ax = fmaf(be[k], wx, ax);
            }
            s_bp[o] = rf(ap);
            s_bx[o] = rf(ax);
        }
    }
    __builtin_amdgcn_sched_barrier(0);

    // ---------- main loop: 16 chunks of 64 b (lanes = b) -------------------
    const int sb = tid >> 3, ss = tid & 7;    // store-phase mapping
    for (int c = 0; c < NCHUNK; ++c) {
        const int cb0 = bbase + c * 64;
        const int b   = cb0 + lane;

        const float x0 = nt[b * ZD + z];      // stride-256B gather, L2-hot
        const float x1 = nt[b * ZD + zpb + w];

        // layer 1: 2->4, tanh, LN (affine folded downstream)
        float h[4];
        #pragma unroll
        for (int i = 0; i < 4; ++i)
            h[i] = fast_tanh(fmaf(x0, s_w1a[i], fmaf(x1, s_w1b[i], s_b1[i])));
        float m = (h[0] + h[1] + h[2] + h[3]) * 0.25f;
        float d0 = h[0] - m, d1 = h[1] - m, d2 = h[2] - m, d3 = h[3] - m;
        float v = (d0 * d0 + d1 * d1 + d2 * d2 + d3 * d3) * 0.25f;
        float rs = rsqrtf(v + 1e-5f);
        float n0 = d0 * rs, n1 = d1 * rs, n2_ = d2 * rs, n3 = d3 * rs;

        // layer 2: 4->4 (g1/be1 folded in), tanh, LN
        float h2[4];
        #pragma unroll
        for (int k = 0; k < 4; ++k) {
            float a = s_b2[k];
            a = fmaf(n0, s_W2[0 * 4 + k], a);
            a = fmaf(n1, s_W2[1 * 4 + k], a);
            a = fmaf(n2_, s_W2[2 * 4 + k], a);
            a = fmaf(n3, s_W2[3 * 4 + k], a);
            h2[k] = fast_tanh(a);
        }
        m = (h2[0] + h2[1] + h2[2] + h2[3]) * 0.25f;
        d0 = h2[0] - m; d1 = h2[1] - m; d2 = h2[2] - m; d3 = h2[3] - m;
        v = (d0 * d0 + d1 * d1 + d2 * d2 + d3 * d3) * 0.25f;
        rs = rsqrtf(v + 1e-5f);
        float u0 = d0 * rs, u1 = d1 * rs, u2 = d2 * rs, u3 = d3 * rs;

        // heads (g2/be2 folded in)
        float l[4], q[4];
        #pragma unroll
        for (int o = 0; o < 4; ++o) {
            float lo = s_bp[o], qo = s_bx[o];
            lo = fmaf(u0, s_Wp[0 * 4 + o], lo);  qo = fmaf(u0, s_Wx[0 * 4 + o], qo);
            lo = fmaf(u1, s_Wp[1 * 4 + o], lo);  qo = fmaf(u1, s_Wx[1 * 4 + o], qo);
            lo = fmaf(u2, s_Wp[2 * 4 + o], lo);  qo = fmaf(u2, s_Wx[2 * 4 + o], qo);
            lo = fmaf(u3, s_Wp[3 * 4 + o], lo);  qo = fmaf(u3, s_Wx[3 * 4 + o], qo);
            l[o] = lo; q[o] = qo;
        }

        // log-softmax / pi / sigmoid
        float mx = fmaxf(fmaxf(l[0], l[1]), fmaxf(l[2], l[3]));
        float e[4], s = 0.0f;
        #pragma unroll
        for (int o = 0; o < 4; ++o) { e[o] = fast_exp(l[o] - mx); s += e[o]; }
        float inv_s = __builtin_amdgcn_rcpf(s);
        float ls = __builtin_amdgcn_logf(s) * LN2;

        float4 ppi, plp, pxi;
        ppi.x = e[0] * inv_s; ppi.y = e[1] * inv_s;
        ppi.z = e[2] * inv_s; ppi.w = e[3] * inv_s;
        plp.x = (l[0] - mx) - ls; plp.y = (l[1] - mx) - ls;
        plp.z = (l[2] - mx) - ls; plp.w = (l[3] - mx) - ls;
        pxi.x = __builtin_amdgcn_rcpf(1.0f + fast_exp(-q[0]));
        pxi.y = __builtin_amdgcn_rcpf(1.0f + fast_exp(-q[1]));
        pxi.z = __builtin_amdgcn_rcpf(1.0f + fast_exp(-q[2]));
        pxi.w = __builtin_amdgcn_rcpf(1.0f + fast_exp(-q[3]));

        // transpose through LDS: stage[b=lane][pair=w][stream][4]
        float* sp = &stage[lane * 100 + w * 12];
        *reinterpret_cast<float4*>(sp)     = ppi;
        *reinterpret_cast<float4*>(sp + 4) = plp;
        *reinterpret_cast<float4*>(sp + 8) = pxi;
        __syncthreads();

        // coalesced full-line stores: tid -> (b=sb, pair=ss)
        const float* rp = &stage[sb * 100 + ss * 12];
        const size_t base = ((size_t)(cb0 + sb) * NPAIR + (size_t)(p0 + ss)) * 4;
        *reinterpret_cast<float4*>(out + base)            = *reinterpret_cast<const float4*>(rp);
        *reinterpret_cast<float4*>(out + OFFW + base)     = *reinterpret_cast<const float4*>(rp + 4);
        *reinterpret_cast<float4*>(out + 2 * OFFW + base) = *reinterpret_cast<const float4*>(rp + 8);
        __syncthreads();   // protect stage before next chunk's writes
    }
}

extern "C" void kernel_launch(void* const* d_in, const int* in_sizes, int n_in,
                              void* d_out, int out_size, void* d_ws, size_t ws_size,
                              hipStream_t stream) {
    const float* nt  = (const float*)d_in[0];
    const float* W1  = (const float*)d_in[1];
    const float* b1  = (const float*)d_in[2];
    const float* g1  = (const float*)d_in[3];
    const float* be1 = (const float*)d_in[4];
    const float* W2  = (const float*)d_in[5];
    const float* b2  = (const float*)d_in[6];
    const float* g2  = (const float*)d_in[7];
    const float* be2 = (const float*)d_in[8];
    const float* Wpi = (const float*)d_in[9];
    const float* bpi = (const float*)d_in[10];
    const float* Wxi = (const float*)d_in[11];
    const float* bxi = (const float*)d_in[12];
    float* out = (float*)d_out;

    // 512 pair-groups x 2 b-halves = 1024 blocks x 512 threads (8 waves)
    dim3 grid(1024), block(512);
    net_kernel<<<grid, block, 0, stream>>>(nt, W1, b1, g1, be1, W2, b2, g2, be2,
                                           Wpi, bpi, Wxi, bxi, out);
}